// Round 1
// baseline (498.255 us; speedup 1.0000x reference)
//
#include <hip/hip_runtime.h>
#include <hip/hip_bf16.h>

typedef unsigned short ushort_t;
typedef float f32x4 __attribute__((ext_vector_type(4)));
typedef __bf16 bf16x8 __attribute__((ext_vector_type(8)));

typedef const __attribute__((address_space(1))) void* gptr_t;
typedef __attribute__((address_space(3))) void* sptr_t;

#define GLD16(g, l) __builtin_amdgcn_global_load_lds((gptr_t)(g), (sptr_t)(l), 16, 0, 0)

// ---------------------------------------------------------------------------
// Kernel 1: global sum of W (fp32 partials, double atomic) -> ws scalar
// ---------------------------------------------------------------------------
__global__ void sum_w_kernel(const float* __restrict__ W, double* __restrict__ out, int n4) {
    int i = blockIdx.x * blockDim.x + threadIdx.x;
    int stride = gridDim.x * blockDim.x;
    float s = 0.f;
    for (; i < n4; i += stride) {
        float4 v = ((const float4*)W)[i];
        s += (v.x + v.y) + (v.z + v.w);
    }
    #pragma unroll
    for (int off = 32; off > 0; off >>= 1) s += __shfl_down(s, off, 64);
    __shared__ float red[4];
    int t = threadIdx.x;
    if ((t & 63) == 0) red[t >> 6] = s;
    __syncthreads();
    if (t == 0) {
        float bs = red[0] + red[1] + red[2] + red[3];
        atomicAdd(out, (double)bs);
    }
}

// ---------------------------------------------------------------------------
// Kernel 2: quantize W -> bf16 {0,1}
// ---------------------------------------------------------------------------
__global__ void quant_w_kernel(const float* __restrict__ W, ushort_t* __restrict__ Wq,
                               const double* __restrict__ sumw, float inv_n, int n4) {
    float mean = (float)(*sumw) * inv_n;
    int i = blockIdx.x * blockDim.x + threadIdx.x;
    int stride = gridDim.x * blockDim.x;
    for (; i < n4; i += stride) {
        float4 v = ((const float4*)W)[i];
        ushort4 o;
        o.x = (v.x > mean) ? 0x3F80 : 0;
        o.y = (v.y > mean) ? 0x3F80 : 0;
        o.z = (v.z > mean) ? 0x3F80 : 0;
        o.w = (v.w > mean) ? 0x3F80 : 0;
        ((ushort4*)Wq)[i] = o;
    }
}

// ---------------------------------------------------------------------------
// Kernel 3: convert x -> bf16 (round-to-nearest)
// ---------------------------------------------------------------------------
__device__ __forceinline__ ushort_t f2bf(float f) {
    __hip_bfloat16 h = __float2bfloat16(f);
    return *(ushort_t*)&h;
}

__global__ void cvt_x_kernel(const float* __restrict__ x, ushort_t* __restrict__ xb, int n4) {
    int i = blockIdx.x * blockDim.x + threadIdx.x;
    int stride = gridDim.x * blockDim.x;
    for (; i < n4; i += stride) {
        float4 v = ((const float4*)x)[i];
        ushort4 o;
        o.x = f2bf(v.x);
        o.y = f2bf(v.y);
        o.z = f2bf(v.z);
        o.w = f2bf(v.w);
        ((ushort4*)xb)[i] = o;
    }
}

// ---------------------------------------------------------------------------
// Kernel 4: quantize b (single block; n = 4096)
// ---------------------------------------------------------------------------
__global__ void quant_b_kernel(const float* __restrict__ b, float* __restrict__ bq, int n) {
    int t = threadIdx.x;
    float s = 0.f;
    for (int i = t; i < n; i += 256) s += b[i];
    #pragma unroll
    for (int off = 32; off > 0; off >>= 1) s += __shfl_down(s, off, 64);
    __shared__ float red[4];
    if ((t & 63) == 0) red[t >> 6] = s;
    __syncthreads();
    float mean = (red[0] + red[1] + red[2] + red[3]) / (float)n;
    for (int i = t; i < n; i += 256) bq[i] = (b[i] > mean) ? 1.0f : 0.0f;
}

// ---------------------------------------------------------------------------
// Kernel 5: bf16 MFMA GEMM  C[M,N] = A[M,K] * B[N,K]^T   (m97 128^2 structure)
// 256 threads = 4 waves (2x2), each wave 64x64 out = 4x4 frags of 16x16x32
// ---------------------------------------------------------------------------
#define BM 128
#define BK 32

__global__ __launch_bounds__(256) void gemm_bf16_kernel(
        const ushort_t* __restrict__ A, const ushort_t* __restrict__ B,
        float* __restrict__ C, int M, int N, int K) {
    __shared__ ushort_t a_lds[BM * BK];
    __shared__ ushort_t b_lds[BM * BK];

    int nbn = N / BM;
    int nwg = gridDim.x;
    int bid = blockIdx.x;
    // XCD-aware swizzle (nwg divisible by 8)
    int cpx = nwg >> 3;
    int wg = (bid & 7) * cpx + (bid >> 3);
    int tm = wg / nbn, tn = wg % nbn;

    int t = threadIdx.x;
    int w = t >> 6, l = t & 63;
    int wr = w >> 1, wc = w & 1;

    // staging: 2 chunks each for A and B; chunk covers 2048 elems (64 rows)
    int e0 = t * 8;
    int r0 = e0 >> 5;        // 0..63
    int c0 = e0 & 31;

    const ushort_t* a_src0 = A + (size_t)(tm * BM + r0) * K + c0;
    const ushort_t* a_src1 = a_src0 + (size_t)64 * K;
    const ushort_t* b_src0 = B + (size_t)(tn * BM + r0) * K + c0;
    const ushort_t* b_src1 = b_src0 + (size_t)64 * K;

    // wave-uniform LDS bases (linear layout, lane x 16B each)
    ushort_t* a_dst0 = a_lds + (w * 64) * 8;
    ushort_t* a_dst1 = a_lds + (256 + w * 64) * 8;
    ushort_t* b_dst0 = b_lds + (w * 64) * 8;
    ushort_t* b_dst1 = b_lds + (256 + w * 64) * 8;

    f32x4 acc[4][4] = {};

    int arow = wr * 64 + (l & 15);
    int bcol = wc * 64 + (l & 15);
    int koff = (l >> 4) * 8;

    for (int kt = 0; kt < K; kt += BK) {
        __syncthreads();
        GLD16(a_src0 + kt, a_dst0);
        GLD16(a_src1 + kt, a_dst1);
        GLD16(b_src0 + kt, b_dst0);
        GLD16(b_src1 + kt, b_dst1);
        __syncthreads();

        bf16x8 af[4], bf_[4];
        #pragma unroll
        for (int fm = 0; fm < 4; ++fm)
            af[fm] = *(const bf16x8*)&a_lds[(arow + fm * 16) * BK + koff];
        #pragma unroll
        for (int fn = 0; fn < 4; ++fn)
            bf_[fn] = *(const bf16x8*)&b_lds[(bcol + fn * 16) * BK + koff];

        #pragma unroll
        for (int fm = 0; fm < 4; ++fm)
            #pragma unroll
            for (int fn = 0; fn < 4; ++fn)
                acc[fm][fn] = __builtin_amdgcn_mfma_f32_16x16x32_bf16(
                    af[fm], bf_[fn], acc[fm][fn], 0, 0, 0);
    }

    // epilogue: C/D layout col = lane&15, row = (lane>>4)*4 + r
    int crow0 = tm * BM + wr * 64 + (l >> 4) * 4;
    int ccol0 = tn * BM + wc * 64 + (l & 15);
    #pragma unroll
    for (int fm = 0; fm < 4; ++fm)
        #pragma unroll
        for (int fn = 0; fn < 4; ++fn)
            #pragma unroll
            for (int r = 0; r < 4; ++r)
                C[(size_t)(crow0 + fm * 16 + r) * N + (ccol0 + fn * 16)] = acc[fm][fn][r];
}

// ---------------------------------------------------------------------------
// Kernel 6: per-row normalize in-place: z = (z + bq - mean) / (sqrt(var_ddof1) + eps)
// one block (256 thr) per row; row length 4096 = 1024 float4
// ---------------------------------------------------------------------------
__device__ __forceinline__ float block_sum_256(float v, float* red) {
    #pragma unroll
    for (int off = 32; off > 0; off >>= 1) v += __shfl_down(v, off, 64);
    int t = threadIdx.x;
    __syncthreads();           // protect red[] reuse across calls
    if ((t & 63) == 0) red[t >> 6] = v;
    __syncthreads();
    return red[0] + red[1] + red[2] + red[3];
}

__global__ void rownorm_kernel(float* __restrict__ z, const float* __restrict__ bq, int N) {
    __shared__ float red[4];
    int row = blockIdx.x;
    float* zr = z + (size_t)row * N;
    int t = threadIdx.x;

    float4 v[4];
    float s = 0.f;
    #pragma unroll
    for (int j = 0; j < 4; ++j) {
        int idx = t + j * 256;
        float4 a = ((const float4*)zr)[idx];
        float4 bb = ((const float4*)bq)[idx];
        a.x += bb.x; a.y += bb.y; a.z += bb.z; a.w += bb.w;
        v[j] = a;
        s += (a.x + a.y) + (a.z + a.w);
    }
    float total = block_sum_256(s, red);
    float mean = total * (1.0f / 4096.0f);

    float q = 0.f;
    #pragma unroll
    for (int j = 0; j < 4; ++j) {
        float dx = v[j].x - mean, dy = v[j].y - mean, dz = v[j].z - mean, dw = v[j].w - mean;
        q += (dx * dx + dy * dy) + (dz * dz + dw * dw);
    }
    float qtot = block_sum_256(q, red);
    float var = qtot * (1.0f / 4095.0f);
    float inv = 1.0f / (sqrtf(var) + 1e-8f);

    #pragma unroll
    for (int j = 0; j < 4; ++j) {
        int idx = t + j * 256;
        float4 o;
        o.x = (v[j].x - mean) * inv;
        o.y = (v[j].y - mean) * inv;
        o.z = (v[j].z - mean) * inv;
        o.w = (v[j].w - mean) * inv;
        ((float4*)zr)[idx] = o;
    }
}

// ---------------------------------------------------------------------------
extern "C" void kernel_launch(void* const* d_in, const int* in_sizes, int n_in,
                              void* d_out, int out_size, void* d_ws, size_t ws_size,
                              hipStream_t stream) {
    const float* x = (const float*)d_in[0];
    const float* W = (const float*)d_in[1];
    const float* b = (const float*)d_in[2];
    float* out = (float*)d_out;

    const int N = in_sizes[2];            // 4096 (OUT)
    const int K = in_sizes[1] / N;        // 4096 (IN)
    const int M = in_sizes[0] / K;        // 8192

    // workspace layout
    char* ws = (char*)d_ws;
    ushort_t* xb = (ushort_t*)ws;                                   // M*K bf16
    ushort_t* wq = (ushort_t*)(ws + (size_t)M * K * 2);             // N*K bf16
    float* bq = (float*)(ws + (size_t)M * K * 2 + (size_t)N * K * 2);  // N fp32
    double* sumw = (double*)(ws + (size_t)M * K * 2 + (size_t)N * K * 2 + (size_t)N * 4);

    hipMemsetAsync(sumw, 0, sizeof(double), stream);
    sum_w_kernel<<<1024, 256, 0, stream>>>(W, sumw, N * K / 4);
    quant_w_kernel<<<2048, 256, 0, stream>>>(W, wq, sumw, 1.0f / (float)((size_t)N * K), N * K / 4);
    cvt_x_kernel<<<2048, 256, 0, stream>>>(x, xb, M * K / 4);
    quant_b_kernel<<<1, 256, 0, stream>>>(b, bq, N);

    int grid = (M / BM) * (N / BM);
    gemm_bf16_kernel<<<grid, 256, 0, stream>>>(xb, wq, out, M, N, K);

    rownorm_kernel<<<M, 256, 0, stream>>>(out, bq, N);
}

// Round 2
// 374.973 us; speedup vs baseline: 1.3288x; 1.3288x over previous
//
#include <hip/hip_runtime.h>
#include <hip/hip_bf16.h>

typedef unsigned short ushort_t;
typedef float f32x4 __attribute__((ext_vector_type(4)));
typedef __bf16 bf16x8 __attribute__((ext_vector_type(8)));

typedef const __attribute__((address_space(1))) void* gptr_t;
typedef __attribute__((address_space(3))) void* sptr_t;

#define GLD16(g, l) __builtin_amdgcn_global_load_lds((gptr_t)(g), (sptr_t)(l), 16, 0, 0)

// ---------------------------------------------------------------------------
// Kernel 1: global sum of W (fp32 partials, double atomic) -> ws scalar
// ---------------------------------------------------------------------------
__global__ void sum_w_kernel(const float* __restrict__ W, double* __restrict__ out, int n4) {
    int i = blockIdx.x * blockDim.x + threadIdx.x;
    int stride = gridDim.x * blockDim.x;
    float s = 0.f;
    for (; i < n4; i += stride) {
        float4 v = ((const float4*)W)[i];
        s += (v.x + v.y) + (v.z + v.w);
    }
    #pragma unroll
    for (int off = 32; off > 0; off >>= 1) s += __shfl_down(s, off, 64);
    __shared__ float red[4];
    int t = threadIdx.x;
    if ((t & 63) == 0) red[t >> 6] = s;
    __syncthreads();
    if (t == 0) {
        float bs = red[0] + red[1] + red[2] + red[3];
        atomicAdd(out, (double)bs);
    }
}

// ---------------------------------------------------------------------------
// Kernel 2: quantize W -> bf16 {0,1}
// ---------------------------------------------------------------------------
__global__ void quant_w_kernel(const float* __restrict__ W, ushort_t* __restrict__ Wq,
                               const double* __restrict__ sumw, float inv_n, int n4) {
    float mean = (float)(*sumw) * inv_n;
    int i = blockIdx.x * blockDim.x + threadIdx.x;
    int stride = gridDim.x * blockDim.x;
    for (; i < n4; i += stride) {
        float4 v = ((const float4*)W)[i];
        ushort4 o;
        o.x = (v.x > mean) ? 0x3F80 : 0;
        o.y = (v.y > mean) ? 0x3F80 : 0;
        o.z = (v.z > mean) ? 0x3F80 : 0;
        o.w = (v.w > mean) ? 0x3F80 : 0;
        ((ushort4*)Wq)[i] = o;
    }
}

// ---------------------------------------------------------------------------
// Kernel 3: convert x -> bf16 (round-to-nearest)
// ---------------------------------------------------------------------------
__device__ __forceinline__ ushort_t f2bf(float f) {
    __hip_bfloat16 h = __float2bfloat16(f);
    return *(ushort_t*)&h;
}

__global__ void cvt_x_kernel(const float* __restrict__ x, ushort_t* __restrict__ xb, int n4) {
    int i = blockIdx.x * blockDim.x + threadIdx.x;
    int stride = gridDim.x * blockDim.x;
    for (; i < n4; i += stride) {
        float4 v = ((const float4*)x)[i];
        ushort4 o;
        o.x = f2bf(v.x);
        o.y = f2bf(v.y);
        o.z = f2bf(v.z);
        o.w = f2bf(v.w);
        ((ushort4*)xb)[i] = o;
    }
}

// ---------------------------------------------------------------------------
// Kernel 4: quantize b (single block; n = 4096)
// ---------------------------------------------------------------------------
__global__ void quant_b_kernel(const float* __restrict__ b, float* __restrict__ bq, int n) {
    int t = threadIdx.x;
    float s = 0.f;
    for (int i = t; i < n; i += 256) s += b[i];
    #pragma unroll
    for (int off = 32; off > 0; off >>= 1) s += __shfl_down(s, off, 64);
    __shared__ float red[4];
    if ((t & 63) == 0) red[t >> 6] = s;
    __syncthreads();
    float mean = (red[0] + red[1] + red[2] + red[3]) / (float)n;
    for (int i = t; i < n; i += 256) bq[i] = (b[i] > mean) ? 1.0f : 0.0f;
}

// ---------------------------------------------------------------------------
// Kernel 5: bf16 MFMA GEMM, 256x256 tile, BK=64, 8 waves (2Mx4N), 8-phase
// schedule with counted vmcnt, st_16x32 LDS swizzle via pre-swizzled source.
//   C[M,N] = A[M,K] * B[N,K]^T
// LDS per buffer: A 32KiB ([half h][128 rows][64 cols], h = (row>>6)&1,
//                 local row = (row>>7)*64 + (row&63))
//                 B 32KiB ([half h][128 rows][64 cols], h = (row>>5)&1,
//                 local row = (row>>6)*32 + (row&31))
// swizzle within each half: byte ^= ((byte>>9)&1)<<5  (flip col bit4 on lr bit2)
// ---------------------------------------------------------------------------
#define PRIO1 __builtin_amdgcn_s_setprio(1)
#define PRIO0 __builtin_amdgcn_s_setprio(0)
#define BAR() __builtin_amdgcn_s_barrier()
#define WAITV4() asm volatile("s_waitcnt vmcnt(4)" ::: "memory")
#define WAITV0() asm volatile("s_waitcnt vmcnt(0)" ::: "memory")
#define UNRL _Pragma("unroll")

__global__ __launch_bounds__(512, 2) void gemm_bf16_256(
        const ushort_t* __restrict__ A, const ushort_t* __restrict__ B,
        float* __restrict__ C, int M, int N, int K) {
    __shared__ ushort_t lds8[65536];   // 128 KiB: [buf][A 16K ushorts | B 16K ushorts]
    char* ldsc = (char*)lds8;

    int nbn = N >> 8;
    int nwg = gridDim.x;
    int bid = blockIdx.x;
    int cpx = nwg >> 3;
    int wg = (bid & 7) * cpx + (bid >> 3);   // XCD swizzle (nwg % 8 == 0)
    int tm = wg / nbn, tn = wg % nbn;

    int t = threadIdx.x;
    int w = t >> 6, l = t & 63;
    int wr = w >> 2, wc = w & 3;             // 2 M-waves x 4 N-waves
    int wrOff = wr * 8192;                   // 64 rows * 128 B
    int wcOff = wc * 4096;                   // 32 rows * 128 B

    // read-side lane offset, swizzle folded in (bit9 of frag addr = lane bit2)
    int laneA = (((l & 15) * 128) + ((l >> 4) * 16)) ^ ((l & 4) << 3);

    // stage-side source offsets (inverse swizzle applied to LDS-linear pos)
    long offA[2][2], offB[2][2];
    UNRL
    for (int c = 0; c < 2; ++c) {
        int o = (t + c * 512) * 16;
        int os = o ^ (((o >> 9) & 1) << 5);
        int lr = os >> 7;
        int col = (os & 127) >> 1;
        UNRL
        for (int h = 0; h < 2; ++h) {
            offA[c][h] = (long)((lr >> 6) * 128 + h * 64 + (lr & 63)) * K + col;
            offB[c][h] = (long)((lr >> 5) * 64 + h * 32 + (lr & 31)) * K + col;
        }
    }

    const ushort_t* srcA = A + (size_t)tm * 256 * K;
    const ushort_t* srcB = B + (size_t)tn * 256 * K;

    f32x4 acc[8][4] = {};
    bf16x8 af[4][2], bf[2][2];

#define STAGE_A(P, H, KIDX) do { \
    GLD16(srcA + offA[0][H] + (KIDX), ldsc + (P)*65536 + (H)*16384 + w*1024); \
    GLD16(srcA + offA[1][H] + (KIDX), ldsc + (P)*65536 + (H)*16384 + 8192 + w*1024); \
} while (0)
#define STAGE_B(P, H, KIDX) do { \
    GLD16(srcB + offB[0][H] + (KIDX), ldsc + (P)*65536 + 32768 + (H)*16384 + w*1024); \
    GLD16(srcB + offB[1][H] + (KIDX), ldsc + (P)*65536 + 32768 + (H)*16384 + 8192 + w*1024); \
} while (0)
#define LOAD_AF(P, H) do { UNRL for (int f = 0; f < 4; ++f) { \
    af[f][0] = *(const bf16x8*)(ldsc + (P)*65536 + (H)*16384 + wrOff + f*2048 + laneA); \
    af[f][1] = *(const bf16x8*)(ldsc + (P)*65536 + (H)*16384 + wrOff + f*2048 + 64 + laneA); \
} } while (0)
#define LOAD_BF(P, H) do { UNRL for (int e = 0; e < 2; ++e) { \
    bf[e][0] = *(const bf16x8*)(ldsc + (P)*65536 + 32768 + (H)*16384 + wcOff + e*2048 + laneA); \
    bf[e][1] = *(const bf16x8*)(ldsc + (P)*65536 + 32768 + (H)*16384 + wcOff + e*2048 + 64 + laneA); \
} } while (0)
#define MFMA_Q(QM, QN) do { UNRL for (int f = 0; f < 4; ++f) UNRL for (int e = 0; e < 2; ++e) { \
    acc[(QM)*4+f][(QN)*2+e] = __builtin_amdgcn_mfma_f32_16x16x32_bf16(af[f][0], bf[e][0], acc[(QM)*4+f][(QN)*2+e], 0, 0, 0); \
    acc[(QM)*4+f][(QN)*2+e] = __builtin_amdgcn_mfma_f32_16x16x32_bf16(af[f][1], bf[e][1], acc[(QM)*4+f][(QN)*2+e], 0, 0, 0); \
} } while (0)
// 4 phases per K-tile. Stage order A0,B0,B1,A1; consume A0B0 / B1 / A1 / B0.
// vmcnt(4) at each phase end => each staged half-tile lands >=2 phases later,
// before its first consumption (gates verified per-phase).
#define TILE(P, PN, KTN) do { \
    LOAD_AF(P, 0); LOAD_BF(P, 0); STAGE_A(PN, 0, KTN); \
    BAR(); PRIO1; MFMA_Q(0, 0); PRIO0; WAITV4(); BAR(); \
    LOAD_BF(P, 1);                STAGE_B(PN, 0, KTN); \
    BAR(); PRIO1; MFMA_Q(0, 1); PRIO0; WAITV4(); BAR(); \
    LOAD_AF(P, 1);                STAGE_B(PN, 1, KTN); \
    BAR(); PRIO1; MFMA_Q(1, 1); PRIO0; WAITV4(); BAR(); \
    LOAD_BF(P, 0);                STAGE_A(PN, 1, KTN); \
    BAR(); PRIO1; MFMA_Q(1, 0); PRIO0; WAITV4(); BAR(); \
} while (0)

    // prologue: stage tile 0 into buf0, drain once (outside main loop)
    STAGE_A(0, 0, 0); STAGE_B(0, 0, 0); STAGE_B(0, 1, 0); STAGE_A(0, 1, 0);
    WAITV0();
    BAR();

    for (int kt = 0; kt < K; kt += 128) {
        int kn1 = kt + 64;
        int kn2 = (kt + 128 < K) ? kt + 128 : 0;   // wrap: redundant, never read
        TILE(0, 1, kn1);
        TILE(1, 0, kn2);
    }

    WAITV0();  // drain trailing stages before epilogue

    // epilogue: C/D layout col = lane&15, row = (lane>>4)*4 + r
    int crow0 = tm * 256 + wr * 128 + (l >> 4) * 4;
    int ccol0 = tn * 256 + wc * 64 + (l & 15);
    UNRL
    for (int fm = 0; fm < 8; ++fm)
        UNRL
        for (int fn = 0; fn < 4; ++fn)
            UNRL
            for (int r = 0; r < 4; ++r)
                C[(size_t)(crow0 + fm * 16 + r) * N + (ccol0 + fn * 16)] = acc[fm][fn][r];
}

// ---------------------------------------------------------------------------
// Kernel 6: per-row normalize in-place: z = (z + bq - mean) / (sqrt(var_ddof1) + eps)
// ---------------------------------------------------------------------------
__device__ __forceinline__ float block_sum_256(float v, float* red) {
    #pragma unroll
    for (int off = 32; off > 0; off >>= 1) v += __shfl_down(v, off, 64);
    int t = threadIdx.x;
    __syncthreads();
    if ((t & 63) == 0) red[t >> 6] = v;
    __syncthreads();
    return red[0] + red[1] + red[2] + red[3];
}

__global__ void rownorm_kernel(float* __restrict__ z, const float* __restrict__ bq, int N) {
    __shared__ float red[4];
    int row = blockIdx.x;
    float* zr = z + (size_t)row * N;
    int t = threadIdx.x;

    float4 v[4];
    float s = 0.f;
    #pragma unroll
    for (int j = 0; j < 4; ++j) {
        int idx = t + j * 256;
        float4 a = ((const float4*)zr)[idx];
        float4 bb = ((const float4*)bq)[idx];
        a.x += bb.x; a.y += bb.y; a.z += bb.z; a.w += bb.w;
        v[j] = a;
        s += (a.x + a.y) + (a.z + a.w);
    }
    float total = block_sum_256(s, red);
    float mean = total * (1.0f / 4096.0f);

    float q = 0.f;
    #pragma unroll
    for (int j = 0; j < 4; ++j) {
        float dx = v[j].x - mean, dy = v[j].y - mean, dz = v[j].z - mean, dw = v[j].w - mean;
        q += (dx * dx + dy * dy) + (dz * dz + dw * dw);
    }
    float qtot = block_sum_256(q, red);
    float var = qtot * (1.0f / 4095.0f);
    float inv = 1.0f / (sqrtf(var) + 1e-8f);

    #pragma unroll
    for (int j = 0; j < 4; ++j) {
        int idx = t + j * 256;
        float4 o;
        o.x = (v[j].x - mean) * inv;
        o.y = (v[j].y - mean) * inv;
        o.z = (v[j].z - mean) * inv;
        o.w = (v[j].w - mean) * inv;
        ((float4*)zr)[idx] = o;
    }
}

// ---------------------------------------------------------------------------
extern "C" void kernel_launch(void* const* d_in, const int* in_sizes, int n_in,
                              void* d_out, int out_size, void* d_ws, size_t ws_size,
                              hipStream_t stream) {
    const float* x = (const float*)d_in[0];
    const float* W = (const float*)d_in[1];
    const float* b = (const float*)d_in[2];
    float* out = (float*)d_out;

    const int N = in_sizes[2];            // 4096 (OUT)
    const int K = in_sizes[1] / N;        // 4096 (IN)
    const int M = in_sizes[0] / K;        // 8192

    // workspace layout
    char* ws = (char*)d_ws;
    ushort_t* xb = (ushort_t*)ws;                                   // M*K bf16
    ushort_t* wq = (ushort_t*)(ws + (size_t)M * K * 2);             // N*K bf16
    float* bq = (float*)(ws + (size_t)M * K * 2 + (size_t)N * K * 2);  // N fp32
    double* sumw = (double*)(ws + (size_t)M * K * 2 + (size_t)N * K * 2 + (size_t)N * 4);

    hipMemsetAsync(sumw, 0, sizeof(double), stream);
    sum_w_kernel<<<1024, 256, 0, stream>>>(W, sumw, N * K / 4);
    quant_w_kernel<<<2048, 256, 0, stream>>>(W, wq, sumw, 1.0f / (float)((size_t)N * K), N * K / 4);
    cvt_x_kernel<<<2048, 256, 0, stream>>>(x, xb, M * K / 4);
    quant_b_kernel<<<1, 256, 0, stream>>>(b, bq, N);

    int grid = (M / 256) * (N / 256);
    gemm_bf16_256<<<grid, 512, 0, stream>>>(xb, wq, out, M, N, K);

    rownorm_kernel<<<M, 256, 0, stream>>>(out, bq, N);
}

// Round 3
// 343.231 us; speedup vs baseline: 1.4517x; 1.0925x over previous
//
#include <hip/hip_runtime.h>
#include <hip/hip_bf16.h>

typedef unsigned short ushort_t;
typedef float f32x4 __attribute__((ext_vector_type(4)));
typedef __bf16 bf16x8 __attribute__((ext_vector_type(8)));

typedef const __attribute__((address_space(1))) void* gptr_t;
typedef __attribute__((address_space(3))) void* sptr_t;

#define GLD16(g, l) __builtin_amdgcn_global_load_lds((gptr_t)(g), (sptr_t)(l), 16, 0, 0)

// ---------------------------------------------------------------------------
// Kernel 1: global sum of W (fp32 partials, double atomic) -> ws scalar
// ---------------------------------------------------------------------------
__global__ void sum_w_kernel(const float* __restrict__ W, double* __restrict__ out, int n4) {
    int i = blockIdx.x * blockDim.x + threadIdx.x;
    int stride = gridDim.x * blockDim.x;
    float s = 0.f;
    for (; i < n4; i += stride) {
        float4 v = ((const float4*)W)[i];
        s += (v.x + v.y) + (v.z + v.w);
    }
    #pragma unroll
    for (int off = 32; off > 0; off >>= 1) s += __shfl_down(s, off, 64);
    __shared__ float red[4];
    int t = threadIdx.x;
    if ((t & 63) == 0) red[t >> 6] = s;
    __syncthreads();
    if (t == 0) {
        float bs = red[0] + red[1] + red[2] + red[3];
        atomicAdd(out, (double)bs);
    }
}

// ---------------------------------------------------------------------------
// Kernel 2: quantize W -> bf16 {0,1}
// ---------------------------------------------------------------------------
__global__ void quant_w_kernel(const float* __restrict__ W, ushort_t* __restrict__ Wq,
                               const double* __restrict__ sumw, float inv_n, int n4) {
    float mean = (float)(*sumw) * inv_n;
    int i = blockIdx.x * blockDim.x + threadIdx.x;
    int stride = gridDim.x * blockDim.x;
    for (; i < n4; i += stride) {
        float4 v = ((const float4*)W)[i];
        ushort4 o;
        o.x = (v.x > mean) ? 0x3F80 : 0;
        o.y = (v.y > mean) ? 0x3F80 : 0;
        o.z = (v.z > mean) ? 0x3F80 : 0;
        o.w = (v.w > mean) ? 0x3F80 : 0;
        ((ushort4*)Wq)[i] = o;
    }
}

// ---------------------------------------------------------------------------
// Kernel 3: convert x -> bf16 (round-to-nearest)
// ---------------------------------------------------------------------------
__device__ __forceinline__ ushort_t f2bf(float f) {
    __hip_bfloat16 h = __float2bfloat16(f);
    return *(ushort_t*)&h;
}

__global__ void cvt_x_kernel(const float* __restrict__ x, ushort_t* __restrict__ xb, int n4) {
    int i = blockIdx.x * blockDim.x + threadIdx.x;
    int stride = gridDim.x * blockDim.x;
    for (; i < n4; i += stride) {
        float4 v = ((const float4*)x)[i];
        ushort4 o;
        o.x = f2bf(v.x);
        o.y = f2bf(v.y);
        o.z = f2bf(v.z);
        o.w = f2bf(v.w);
        ((ushort4*)xb)[i] = o;
    }
}

// ---------------------------------------------------------------------------
// Kernel 4: quantize b (single block; n = 4096)
// ---------------------------------------------------------------------------
__global__ void quant_b_kernel(const float* __restrict__ b, float* __restrict__ bq, int n) {
    int t = threadIdx.x;
    float s = 0.f;
    for (int i = t; i < n; i += 256) s += b[i];
    #pragma unroll
    for (int off = 32; off > 0; off >>= 1) s += __shfl_down(s, off, 64);
    __shared__ float red[4];
    if ((t & 63) == 0) red[t >> 6] = s;
    __syncthreads();
    float mean = (red[0] + red[1] + red[2] + red[3]) / (float)n;
    for (int i = t; i < n; i += 256) bq[i] = (b[i] > mean) ? 1.0f : 0.0f;
}

// ---------------------------------------------------------------------------
// Kernel 5: bf16 MFMA GEMM, 256x256 tile, BK=64, 8 waves (2Mx4N), 8-phase
// schedule with counted vmcnt.  C[M,N] = A[M,K] * B[N,K]^T
// LDS swizzle (full-granule): byte ^= ((byte>>3) & 0x70) — XOR row bits 0-2
// (addr bits 7-9) into 16B-granule bits 4-6. Involution, row-preserving.
// For fixed read-quad q, rows 0..15 -> granule q^(r&7): 8 lanes/granule =
// wave64 b128 floor -> zero extra bank cycles.
// ---------------------------------------------------------------------------
#define PRIO1 __builtin_amdgcn_s_setprio(1)
#define PRIO0 __builtin_amdgcn_s_setprio(0)
#define BAR() __builtin_amdgcn_s_barrier()
#define WAITV4() asm volatile("s_waitcnt vmcnt(4)" ::: "memory")
#define WAITV0() asm volatile("s_waitcnt vmcnt(0)" ::: "memory")
#define UNRL _Pragma("unroll")

__global__ __launch_bounds__(512, 2) void gemm_bf16_256(
        const ushort_t* __restrict__ A, const ushort_t* __restrict__ B,
        float* __restrict__ C, int M, int N, int K) {
    __shared__ ushort_t lds8[65536];   // 128 KiB: [buf][A 16K ushorts | B 16K ushorts]
    char* ldsc = (char*)lds8;

    int nbn = N >> 8;
    int nwg = gridDim.x;
    int bid = blockIdx.x;
    int cpx = nwg >> 3;
    int wg = (bid & 7) * cpx + (bid >> 3);   // XCD swizzle (nwg % 8 == 0)
    int tm = wg / nbn, tn = wg % nbn;

    int t = threadIdx.x;
    int w = t >> 6, l = t & 63;
    int wr = w >> 2, wc = w & 3;             // 2 M-waves x 4 N-waves
    int wrOff = wr * 8192;                   // 64 rows * 128 B
    int wcOff = wc * 4096;                   // 32 rows * 128 B

    // read-side lane offsets, full-granule swizzle folded in
    int baseL = ((l & 15) * 128) + ((l >> 4) * 16);
    int laneA0 = baseL ^ ((l & 7) << 4);     // K elems 0..31
    int laneA1 = laneA0 ^ 64;                // K elems 32..63 (bit6 flip pre-swz)

    // stage-side source offsets (inverse swizzle = same involution)
    long offA[2][2], offB[2][2];
    UNRL
    for (int c = 0; c < 2; ++c) {
        int o = (t + c * 512) * 16;
        int os = o ^ ((o >> 3) & 0x70);
        int lr = os >> 7;
        int col = (os & 127) >> 1;
        UNRL
        for (int h = 0; h < 2; ++h) {
            offA[c][h] = (long)((lr >> 6) * 128 + h * 64 + (lr & 63)) * K + col;
            offB[c][h] = (long)((lr >> 5) * 64 + h * 32 + (lr & 31)) * K + col;
        }
    }

    const ushort_t* srcA = A + (size_t)tm * 256 * K;
    const ushort_t* srcB = B + (size_t)tn * 256 * K;

    f32x4 acc[8][4] = {};
    bf16x8 af[4][2], bf[2][2];

#define STAGE_A(P, H, KIDX) do { \
    GLD16(srcA + offA[0][H] + (KIDX), ldsc + (P)*65536 + (H)*16384 + w*1024); \
    GLD16(srcA + offA[1][H] + (KIDX), ldsc + (P)*65536 + (H)*16384 + 8192 + w*1024); \
} while (0)
#define STAGE_B(P, H, KIDX) do { \
    GLD16(srcB + offB[0][H] + (KIDX), ldsc + (P)*65536 + 32768 + (H)*16384 + w*1024); \
    GLD16(srcB + offB[1][H] + (KIDX), ldsc + (P)*65536 + 32768 + (H)*16384 + 8192 + w*1024); \
} while (0)
#define LOAD_AF(P, H) do { UNRL for (int f = 0; f < 4; ++f) { \
    af[f][0] = *(const bf16x8*)(ldsc + (P)*65536 + (H)*16384 + wrOff + f*2048 + laneA0); \
    af[f][1] = *(const bf16x8*)(ldsc + (P)*65536 + (H)*16384 + wrOff + f*2048 + laneA1); \
} } while (0)
#define LOAD_BF(P, H) do { UNRL for (int e = 0; e < 2; ++e) { \
    bf[e][0] = *(const bf16x8*)(ldsc + (P)*65536 + 32768 + (H)*16384 + wcOff + e*2048 + laneA0); \
    bf[e][1] = *(const bf16x8*)(ldsc + (P)*65536 + 32768 + (H)*16384 + wcOff + e*2048 + laneA1); \
} } while (0)
#define MFMA_Q(QM, QN) do { UNRL for (int f = 0; f < 4; ++f) UNRL for (int e = 0; e < 2; ++e) { \
    acc[(QM)*4+f][(QN)*2+e] = __builtin_amdgcn_mfma_f32_16x16x32_bf16(af[f][0], bf[e][0], acc[(QM)*4+f][(QN)*2+e], 0, 0, 0); \
    acc[(QM)*4+f][(QN)*2+e] = __builtin_amdgcn_mfma_f32_16x16x32_bf16(af[f][1], bf[e][1], acc[(QM)*4+f][(QN)*2+e], 0, 0, 0); \
} } while (0)
// 4 phases per K-tile. Stage order A0,B0,B1,A1; consume A0B0 / B1 / A1 / B0.
// vmcnt(4) at each phase end => each staged half-tile lands >=2 phases later,
// before its first consumption (gates verified per-phase).
#define TILE(P, PN, KTN) do { \
    LOAD_AF(P, 0); LOAD_BF(P, 0); STAGE_A(PN, 0, KTN); \
    BAR(); PRIO1; MFMA_Q(0, 0); PRIO0; WAITV4(); BAR(); \
    LOAD_BF(P, 1);                STAGE_B(PN, 0, KTN); \
    BAR(); PRIO1; MFMA_Q(0, 1); PRIO0; WAITV4(); BAR(); \
    LOAD_AF(P, 1);                STAGE_B(PN, 1, KTN); \
    BAR(); PRIO1; MFMA_Q(1, 1); PRIO0; WAITV4(); BAR(); \
    LOAD_BF(P, 0);                STAGE_A(PN, 1, KTN); \
    BAR(); PRIO1; MFMA_Q(1, 0); PRIO0; WAITV4(); BAR(); \
} while (0)

    // prologue: stage tile 0 into buf0, drain once (outside main loop)
    STAGE_A(0, 0, 0); STAGE_B(0, 0, 0); STAGE_B(0, 1, 0); STAGE_A(0, 1, 0);
    WAITV0();
    BAR();

    for (int kt = 0; kt < K; kt += 128) {
        int kn1 = kt + 64;
        int kn2 = (kt + 128 < K) ? kt + 128 : 0;   // wrap: redundant, never read
        TILE(0, 1, kn1);
        TILE(1, 0, kn2);
    }

    WAITV0();  // drain trailing stages before epilogue

    // epilogue: C/D layout col = lane&15, row = (lane>>4)*4 + r
    int crow0 = tm * 256 + wr * 128 + (l >> 4) * 4;
    int ccol0 = tn * 256 + wc * 64 + (l & 15);
    UNRL
    for (int fm = 0; fm < 8; ++fm)
        UNRL
        for (int fn = 0; fn < 4; ++fn)
            UNRL
            for (int r = 0; r < 4; ++r)
                C[(size_t)(crow0 + fm * 16 + r) * N + (ccol0 + fn * 16)] = acc[fm][fn][r];
}

// ---------------------------------------------------------------------------
// Kernel 6: per-row normalize in-place: z = (z + bq - mean) / (sqrt(var_ddof1) + eps)
// ---------------------------------------------------------------------------
__device__ __forceinline__ float block_sum_256(float v, float* red) {
    #pragma unroll
    for (int off = 32; off > 0; off >>= 1) v += __shfl_down(v, off, 64);
    int t = threadIdx.x;
    __syncthreads();
    if ((t & 63) == 0) red[t >> 6] = v;
    __syncthreads();
    return red[0] + red[1] + red[2] + red[3];
}

__global__ void rownorm_kernel(float* __restrict__ z, const float* __restrict__ bq, int N) {
    __shared__ float red[4];
    int row = blockIdx.x;
    float* zr = z + (size_t)row * N;
    int t = threadIdx.x;

    float4 v[4];
    float s = 0.f;
    #pragma unroll
    for (int j = 0; j < 4; ++j) {
        int idx = t + j * 256;
        float4 a = ((const float4*)zr)[idx];
        float4 bb = ((const float4*)bq)[idx];
        a.x += bb.x; a.y += bb.y; a.z += bb.z; a.w += bb.w;
        v[j] = a;
        s += (a.x + a.y) + (a.z + a.w);
    }
    float total = block_sum_256(s, red);
    float mean = total * (1.0f / 4096.0f);

    float q = 0.f;
    #pragma unroll
    for (int j = 0; j < 4; ++j) {
        float dx = v[j].x - mean, dy = v[j].y - mean, dz = v[j].z - mean, dw = v[j].w - mean;
        q += (dx * dx + dy * dy) + (dz * dz + dw * dw);
    }
    float qtot = block_sum_256(q, red);
    float var = qtot * (1.0f / 4095.0f);
    float inv = 1.0f / (sqrtf(var) + 1e-8f);

    #pragma unroll
    for (int j = 0; j < 4; ++j) {
        int idx = t + j * 256;
        float4 o;
        o.x = (v[j].x - mean) * inv;
        o.y = (v[j].y - mean) * inv;
        o.z = (v[j].z - mean) * inv;
        o.w = (v[j].w - mean) * inv;
        ((float4*)zr)[idx] = o;
    }
}

// ---------------------------------------------------------------------------
extern "C" void kernel_launch(void* const* d_in, const int* in_sizes, int n_in,
                              void* d_out, int out_size, void* d_ws, size_t ws_size,
                              hipStream_t stream) {
    const float* x = (const float*)d_in[0];
    const float* W = (const float*)d_in[1];
    const float* b = (const float*)d_in[2];
    float* out = (float*)d_out;

    const int N = in_sizes[2];            // 4096 (OUT)
    const int K = in_sizes[1] / N;        // 4096 (IN)
    const int M = in_sizes[0] / K;        // 8192

    // workspace layout
    char* ws = (char*)d_ws;
    ushort_t* xb = (ushort_t*)ws;                                   // M*K bf16
    ushort_t* wq = (ushort_t*)(ws + (size_t)M * K * 2);             // N*K bf16
    float* bq = (float*)(ws + (size_t)M * K * 2 + (size_t)N * K * 2);  // N fp32
    double* sumw = (double*)(ws + (size_t)M * K * 2 + (size_t)N * K * 2 + (size_t)N * 4);

    hipMemsetAsync(sumw, 0, sizeof(double), stream);
    sum_w_kernel<<<1024, 256, 0, stream>>>(W, sumw, N * K / 4);
    quant_w_kernel<<<2048, 256, 0, stream>>>(W, wq, sumw, 1.0f / (float)((size_t)N * K), N * K / 4);
    cvt_x_kernel<<<2048, 256, 0, stream>>>(x, xb, M * K / 4);
    quant_b_kernel<<<1, 256, 0, stream>>>(b, bq, N);

    int grid = (M / 256) * (N / 256);
    gemm_bf16_256<<<grid, 512, 0, stream>>>(xb, wq, out, M, N, K);

    rownorm_kernel<<<M, 256, 0, stream>>>(out, bq, N);
}

// Round 4
// 334.721 us; speedup vs baseline: 1.4886x; 1.0254x over previous
//
#include <hip/hip_runtime.h>
#include <hip/hip_bf16.h>

typedef unsigned short ushort_t;
typedef float f32x4 __attribute__((ext_vector_type(4)));
typedef __bf16 bf16x8 __attribute__((ext_vector_type(8)));

typedef const __attribute__((address_space(1))) void* gptr_t;
typedef __attribute__((address_space(3))) void* sptr_t;

#define GLD16(g, l) __builtin_amdgcn_global_load_lds((gptr_t)(g), (sptr_t)(l), 16, 0, 0)

// ---------------------------------------------------------------------------
// Kernel 1: global sum of W (fp32 partials, double atomic) -> ws scalar
// ---------------------------------------------------------------------------
__global__ void sum_w_kernel(const float* __restrict__ W, double* __restrict__ out, int n4) {
    int i = blockIdx.x * blockDim.x + threadIdx.x;
    int stride = gridDim.x * blockDim.x;
    float s = 0.f;
    for (; i < n4; i += stride) {
        float4 v = ((const float4*)W)[i];
        s += (v.x + v.y) + (v.z + v.w);
    }
    #pragma unroll
    for (int off = 32; off > 0; off >>= 1) s += __shfl_down(s, off, 64);
    __shared__ float red[4];
    int t = threadIdx.x;
    if ((t & 63) == 0) red[t >> 6] = s;
    __syncthreads();
    if (t == 0) {
        float bs = red[0] + red[1] + red[2] + red[3];
        atomicAdd(out, (double)bs);
    }
}

// ---------------------------------------------------------------------------
// Kernel 2: quantize W -> bf16 {0,1}
// ---------------------------------------------------------------------------
__global__ void quant_w_kernel(const float* __restrict__ W, ushort_t* __restrict__ Wq,
                               const double* __restrict__ sumw, float inv_n, int n4) {
    float mean = (float)(*sumw) * inv_n;
    int i = blockIdx.x * blockDim.x + threadIdx.x;
    int stride = gridDim.x * blockDim.x;
    for (; i < n4; i += stride) {
        float4 v = ((const float4*)W)[i];
        ushort4 o;
        o.x = (v.x > mean) ? 0x3F80 : 0;
        o.y = (v.y > mean) ? 0x3F80 : 0;
        o.z = (v.z > mean) ? 0x3F80 : 0;
        o.w = (v.w > mean) ? 0x3F80 : 0;
        ((ushort4*)Wq)[i] = o;
    }
}

// ---------------------------------------------------------------------------
// Kernel 3: convert x -> bf16 (round-to-nearest)
// ---------------------------------------------------------------------------
__device__ __forceinline__ ushort_t f2bf(float f) {
    __hip_bfloat16 h = __float2bfloat16(f);
    return *(ushort_t*)&h;
}

__global__ void cvt_x_kernel(const float* __restrict__ x, ushort_t* __restrict__ xb, int n4) {
    int i = blockIdx.x * blockDim.x + threadIdx.x;
    int stride = gridDim.x * blockDim.x;
    for (; i < n4; i += stride) {
        float4 v = ((const float4*)x)[i];
        ushort4 o;
        o.x = f2bf(v.x);
        o.y = f2bf(v.y);
        o.z = f2bf(v.z);
        o.w = f2bf(v.w);
        ((ushort4*)xb)[i] = o;
    }
}

// ---------------------------------------------------------------------------
// Kernel 4: quantize b (single block; n = 4096)
// ---------------------------------------------------------------------------
__global__ void quant_b_kernel(const float* __restrict__ b, float* __restrict__ bq, int n) {
    int t = threadIdx.x;
    float s = 0.f;
    for (int i = t; i < n; i += 256) s += b[i];
    #pragma unroll
    for (int off = 32; off > 0; off >>= 1) s += __shfl_down(s, off, 64);
    __shared__ float red[4];
    if ((t & 63) == 0) red[t >> 6] = s;
    __syncthreads();
    float mean = (red[0] + red[1] + red[2] + red[3]) / (float)n;
    for (int i = t; i < n; i += 256) bq[i] = (b[i] > mean) ? 1.0f : 0.0f;
}

// ---------------------------------------------------------------------------
// Kernel 5: bf16 MFMA GEMM, 256x256 tile, BK=64, 8 waves (2Mx4N), 4 phases
// per K-tile, ONE barrier per phase (phase-end only), counted vmcnt(4).
//   C[M,N] = A[M,K] * B[N,K]^T
// LDS swizzle (full-granule): byte ^= ((byte>>3) & 0x70). Involution,
// row-preserving; 8 lanes/16B-granule = wave64 b128 floor (0 conflicts, R3).
// Phase k: {ds_read frags for this phase's MFMA quadrant | issue one
// half-tile stage into buffer P'} then MFMA (lgkm-staggered by compiler,
// overlaps reads), then vmcnt(4)+BAR. Gate analysis (unchanged from R2):
// stage order A0',B0',B1',A1'; vmcnt(4) at each phase end => each staged
// half-tile lands >=2 phases before first consumption.
// B0 frags held in bf0[][] across the whole tile (no ph4 re-read).
// ---------------------------------------------------------------------------
#define PRIO1 __builtin_amdgcn_s_setprio(1)
#define PRIO0 __builtin_amdgcn_s_setprio(0)
#define BAR() __builtin_amdgcn_s_barrier()
#define WAITV4() asm volatile("s_waitcnt vmcnt(4)" ::: "memory")
#define WAITV0() asm volatile("s_waitcnt vmcnt(0)" ::: "memory")
#define UNRL _Pragma("unroll")

__global__ __launch_bounds__(512, 2) void gemm_bf16_256(
        const ushort_t* __restrict__ A, const ushort_t* __restrict__ B,
        float* __restrict__ C, int M, int N, int K) {
    __shared__ ushort_t lds8[65536];   // 128 KiB: [buf][A 16K ushorts | B 16K ushorts]
    char* ldsc = (char*)lds8;

    int nbn = N >> 8;
    int nwg = gridDim.x;
    int bid = blockIdx.x;
    int cpx = nwg >> 3;
    int wg = (bid & 7) * cpx + (bid >> 3);   // XCD swizzle (nwg % 8 == 0)
    int tm = wg / nbn, tn = wg % nbn;

    int t = threadIdx.x;
    int w = t >> 6, l = t & 63;
    int wr = w >> 2, wc = w & 3;             // 2 M-waves x 4 N-waves
    int wrOff = wr * 8192;                   // 64 rows * 128 B
    int wcOff = wc * 4096;                   // 32 rows * 128 B

    // read-side lane offsets, full-granule swizzle folded in
    int baseL = ((l & 15) * 128) + ((l >> 4) * 16);
    int laneA0 = baseL ^ ((l & 7) << 4);     // K elems 0..31
    int laneA1 = laneA0 ^ 64;                // K elems 32..63 (bit6 flip pre-swz)

    // stage-side source offsets (inverse swizzle = same involution), 32-bit
    int offA[2][2], offB[2][2];
    UNRL
    for (int c = 0; c < 2; ++c) {
        int o = (t + c * 512) * 16;
        int os = o ^ ((o >> 3) & 0x70);
        int lr = os >> 7;
        int col = (os & 127) >> 1;
        UNRL
        for (int h = 0; h < 2; ++h) {
            offA[c][h] = ((lr >> 6) * 128 + h * 64 + (lr & 63)) * K + col;
            offB[c][h] = ((lr >> 5) * 64 + h * 32 + (lr & 31)) * K + col;
        }
    }

    const ushort_t* srcA = A + (size_t)tm * 256 * K;
    const ushort_t* srcB = B + (size_t)tn * 256 * K;

    f32x4 acc[8][4] = {};
    bf16x8 af[4][2], bf0[2][2], bf1[2][2];

#define STAGE_A(P, H, KIDX) do { \
    GLD16(srcA + (size_t)offA[0][H] + (KIDX), ldsc + (P)*65536 + (H)*16384 + w*1024); \
    GLD16(srcA + (size_t)offA[1][H] + (KIDX), ldsc + (P)*65536 + (H)*16384 + 8192 + w*1024); \
} while (0)
#define STAGE_B(P, H, KIDX) do { \
    GLD16(srcB + (size_t)offB[0][H] + (KIDX), ldsc + (P)*65536 + 32768 + (H)*16384 + w*1024); \
    GLD16(srcB + (size_t)offB[1][H] + (KIDX), ldsc + (P)*65536 + 32768 + (H)*16384 + 8192 + w*1024); \
} while (0)
#define LOAD_AF(P, H) do { UNRL for (int f = 0; f < 4; ++f) { \
    af[f][0] = *(const bf16x8*)(ldsc + (P)*65536 + (H)*16384 + wrOff + f*2048 + laneA0); \
    af[f][1] = *(const bf16x8*)(ldsc + (P)*65536 + (H)*16384 + wrOff + f*2048 + laneA1); \
} } while (0)
#define LOAD_BF(BF, P, H) do { UNRL for (int e = 0; e < 2; ++e) { \
    BF[e][0] = *(const bf16x8*)(ldsc + (P)*65536 + 32768 + (H)*16384 + wcOff + e*2048 + laneA0); \
    BF[e][1] = *(const bf16x8*)(ldsc + (P)*65536 + 32768 + (H)*16384 + wcOff + e*2048 + laneA1); \
} } while (0)
#define MFMA_Q(QM, QN, BF) do { UNRL for (int f = 0; f < 4; ++f) UNRL for (int e = 0; e < 2; ++e) { \
    acc[(QM)*4+f][(QN)*2+e] = __builtin_amdgcn_mfma_f32_16x16x32_bf16(af[f][0], BF[e][0], acc[(QM)*4+f][(QN)*2+e], 0, 0, 0); \
    acc[(QM)*4+f][(QN)*2+e] = __builtin_amdgcn_mfma_f32_16x16x32_bf16(af[f][1], BF[e][1], acc[(QM)*4+f][(QN)*2+e], 0, 0, 0); \
} } while (0)

#define TILE(P, PN, KTN) do { \
    LOAD_AF(P, 0); LOAD_BF(bf0, P, 0); STAGE_A(PN, 0, KTN); \
    PRIO1; MFMA_Q(0, 0, bf0); PRIO0; WAITV4(); BAR(); \
    LOAD_BF(bf1, P, 1);                STAGE_B(PN, 0, KTN); \
    PRIO1; MFMA_Q(0, 1, bf1); PRIO0; WAITV4(); BAR(); \
    LOAD_AF(P, 1);                     STAGE_B(PN, 1, KTN); \
    PRIO1; MFMA_Q(1, 1, bf1); PRIO0; WAITV4(); BAR(); \
                                       STAGE_A(PN, 1, KTN); \
    PRIO1; MFMA_Q(1, 0, bf0); PRIO0; WAITV4(); BAR(); \
} while (0)

    // prologue: stage tile 0 into buf0, drain once (outside main loop)
    STAGE_A(0, 0, 0); STAGE_B(0, 0, 0); STAGE_B(0, 1, 0); STAGE_A(0, 1, 0);
    WAITV0();
    BAR();

    for (int kt = 0; kt < K; kt += 128) {
        int kn1 = kt + 64;
        int kn2 = (kt + 128 < K) ? kt + 128 : 0;   // wrap: redundant, never read
        TILE(0, 1, kn1);
        TILE(1, 0, kn2);
    }

    WAITV0();  // drain trailing stages before epilogue

    // epilogue: C/D layout col = lane&15, row = (lane>>4)*4 + r
    int crow0 = tm * 256 + wr * 128 + (l >> 4) * 4;
    int ccol0 = tn * 256 + wc * 64 + (l & 15);
    UNRL
    for (int fm = 0; fm < 8; ++fm)
        UNRL
        for (int fn = 0; fn < 4; ++fn)
            UNRL
            for (int r = 0; r < 4; ++r)
                C[(size_t)(crow0 + fm * 16 + r) * N + (ccol0 + fn * 16)] = acc[fm][fn][r];
}

// ---------------------------------------------------------------------------
// Kernel 6: per-row normalize in-place: z = (z + bq - mean) / (sqrt(var_ddof1) + eps)
// ---------------------------------------------------------------------------
__device__ __forceinline__ float block_sum_256(float v, float* red) {
    #pragma unroll
    for (int off = 32; off > 0; off >>= 1) v += __shfl_down(v, off, 64);
    int t = threadIdx.x;
    __syncthreads();
    if ((t & 63) == 0) red[t >> 6] = v;
    __syncthreads();
    return red[0] + red[1] + red[2] + red[3];
}

__global__ void rownorm_kernel(float* __restrict__ z, const float* __restrict__ bq, int N) {
    __shared__ float red[4];
    int row = blockIdx.x;
    float* zr = z + (size_t)row * N;
    int t = threadIdx.x;

    float4 v[4];
    float s = 0.f;
    #pragma unroll
    for (int j = 0; j < 4; ++j) {
        int idx = t + j * 256;
        float4 a = ((const float4*)zr)[idx];
        float4 bb = ((const float4*)bq)[idx];
        a.x += bb.x; a.y += bb.y; a.z += bb.z; a.w += bb.w;
        v[j] = a;
        s += (a.x + a.y) + (a.z + a.w);
    }
    float total = block_sum_256(s, red);
    float mean = total * (1.0f / 4096.0f);

    float q = 0.f;
    #pragma unroll
    for (int j = 0; j < 4; ++j) {
        float dx = v[j].x - mean, dy = v[j].y - mean, dz = v[j].z - mean, dw = v[j].w - mean;
        q += (dx * dx + dy * dy) + (dz * dz + dw * dw);
    }
    float qtot = block_sum_256(q, red);
    float var = qtot * (1.0f / 4095.0f);
    float inv = 1.0f / (sqrtf(var) + 1e-8f);

    #pragma unroll
    for (int j = 0; j < 4; ++j) {
        int idx = t + j * 256;
        float4 o;
        o.x = (v[j].x - mean) * inv;
        o.y = (v[j].y - mean) * inv;
        o.z = (v[j].z - mean) * inv;
        o.w = (v[j].w - mean) * inv;
        ((float4*)zr)[idx] = o;
    }
}

// ---------------------------------------------------------------------------
extern "C" void kernel_launch(void* const* d_in, const int* in_sizes, int n_in,
                              void* d_out, int out_size, void* d_ws, size_t ws_size,
                              hipStream_t stream) {
    const float* x = (const float*)d_in[0];
    const float* W = (const float*)d_in[1];
    const float* b = (const float*)d_in[2];
    float* out = (float*)d_out;

    const int N = in_sizes[2];            // 4096 (OUT)
    const int K = in_sizes[1] / N;        // 4096 (IN)
    const int M = in_sizes[0] / K;        // 8192

    // workspace layout
    char* ws = (char*)d_ws;
    ushort_t* xb = (ushort_t*)ws;                                   // M*K bf16
    ushort_t* wq = (ushort_t*)(ws + (size_t)M * K * 2);             // N*K bf16
    float* bq = (float*)(ws + (size_t)M * K * 2 + (size_t)N * K * 2);  // N fp32
    double* sumw = (double*)(ws + (size_t)M * K * 2 + (size_t)N * K * 2 + (size_t)N * 4);

    hipMemsetAsync(sumw, 0, sizeof(double), stream);
    sum_w_kernel<<<1024, 256, 0, stream>>>(W, sumw, N * K / 4);
    quant_w_kernel<<<2048, 256, 0, stream>>>(W, wq, sumw, 1.0f / (float)((size_t)N * K), N * K / 4);
    cvt_x_kernel<<<2048, 256, 0, stream>>>(x, xb, M * K / 4);
    quant_b_kernel<<<1, 256, 0, stream>>>(b, bq, N);

    int grid = (M / 256) * (N / 256);
    gemm_bf16_256<<<grid, 512, 0, stream>>>(xb, wq, out, M, N, K);

    rownorm_kernel<<<M, 256, 0, stream>>>(out, bq, N);
}